// Round 8
// baseline (262.724 us; speedup 1.0000x reference)
//
#include <hip/hip_runtime.h>
#include <hip/hip_fp16.h>
#include <cstdint>
#include <cstddef>

#define NN 100000
#define NE 1600000
#define D 128
#define NBK 782            // ceil(NN / 128) buckets of 128 nodes
#define NBLK_P 512         // partition blocks
#define EPB 3125           // edges per partition block (512*3125 = 1.6M exact)

typedef _Float16 half8 __attribute__((ext_vector_type(8)));
typedef _Float16 half4v __attribute__((ext_vector_type(4)));
typedef float f32x4 __attribute__((ext_vector_type(4)));

// ---------------- workspace layout (bytes) ----------------
// part  : NE u32      @ 0          (6,400,000)   } dead after p4_csr; overlapped by h
// offs  : 512*782 u32 @ 6,400,000  (1,601,536)   }
// base  : 783 u32     @ 8,100,000  (    3,132)   }
// h'    : NN*128 f16  @ 0          (25,600,000)  = dinv[row] * (x@W1), written after CSR
// z'    : NN*2 f32    @ 25,600,000 (   800,000)  = dinv[row] * (relu(agg+b1)@W2)
// dinv  : NN f32      @ 26,400,000 (   400,000)
// rp    : NN+1 u32    @ 26,800,000 (   400,004)
// col   : NE u32      @ 27,200,016 ( 6,400,000)
// Wt    : 128*128 f16 @ 33,600,016 (    32,768)  -> total 33,632,784

// P1: per-block LDS histogram over dst buckets (no global atomics).
__launch_bounds__(256)
__global__ void p1_count_k(const int* __restrict__ ei, unsigned* __restrict__ offs) {
    __shared__ unsigned hist[NBK];
    int tid = threadIdx.x, b = blockIdx.x;
    for (int k = tid; k < NBK; k += 256) hist[k] = 0u;
    __syncthreads();
    int e0 = b * EPB;
    for (int i = tid; i < EPB; i += 256) {
        int d = ei[NE + e0 + i];
        atomicAdd(&hist[d >> 7], 1u);
    }
    __syncthreads();
    for (int k = tid; k < NBK; k += 256) offs[(size_t)b * NBK + k] = hist[k];
}

// P2a: block per bucket; 512 threads load the 512 per-block counts + LDS scan.
__launch_bounds__(512)
__global__ void p2a_k(unsigned* __restrict__ offs, unsigned* __restrict__ base) {
    __shared__ unsigned sh[512];
    int t = threadIdx.x, k = blockIdx.x;
    unsigned v = offs[(size_t)t * NBK + k];
    sh[t] = v;
    __syncthreads();
    for (int off = 1; off < 512; off <<= 1) {
        unsigned u = (t >= off) ? sh[t - off] : 0u;
        __syncthreads();
        sh[t] += u;
        __syncthreads();
    }
    offs[(size_t)t * NBK + k] = sh[t] - v;   // exclusive
    if (t == 511) base[k] = sh[511];         // bucket total
}

// P2b: exclusive scan of bucket totals; base[NBK] = NE.
__global__ void p2b_k(unsigned* __restrict__ base) {
    __shared__ unsigned sh[1024];
    int t = threadIdx.x;
    unsigned v = (t < NBK) ? base[t] : 0u;
    sh[t] = v;
    __syncthreads();
    for (int off = 1; off < 1024; off <<= 1) {
        unsigned u = (t >= off) ? sh[t - off] : 0u;
        __syncthreads();
        sh[t] += u;
        __syncthreads();
    }
    if (t < NBK) base[t] = sh[t] - v;
    if (t == NBK) base[NBK] = sh[NBK - 1];
}

// P3: scatter packed edges into bucket-partitioned order via LDS running counters.
__launch_bounds__(256)
__global__ void p3_scatter_k(const int* __restrict__ ei, const unsigned* __restrict__ offs,
                             const unsigned* __restrict__ base, unsigned* __restrict__ part) {
    __shared__ unsigned lcnt[NBK];
    int tid = threadIdx.x, b = blockIdx.x;
    for (int k = tid; k < NBK; k += 256) lcnt[k] = base[k] + offs[(size_t)b * NBK + k];
    __syncthreads();
    int e0 = b * EPB;
    for (int i = tid; i < EPB; i += 256) {
        int s = ei[e0 + i];
        int d = ei[NE + e0 + i];
        unsigned pos = atomicAdd(&lcnt[d >> 7], 1u);
        part[pos] = (unsigned)s | ((unsigned)(d & 127) << 20);
    }
}

// P4: one block per bucket. Count per node in LDS, scan, emit rp/dinv, regroup col.
__launch_bounds__(256)
__global__ void p4_csr_k(const unsigned* __restrict__ part, const unsigned* __restrict__ base,
                         unsigned* __restrict__ rp, float* __restrict__ dinv,
                         unsigned* __restrict__ col) {
    __shared__ unsigned c[128], p[128], run[128];
    int tid = threadIdx.x, k = blockIdx.x;
    int n0 = k << 7;
    int nodes = (NN - n0 < 128) ? (NN - n0) : 128;
    unsigned e0 = base[k], e1 = base[k + 1];

    if (tid < 128) c[tid] = 0u;
    __syncthreads();
    for (unsigned e = e0 + tid; e < e1; e += 256)
        atomicAdd(&c[(part[e] >> 20) & 127], 1u);
    __syncthreads();

    unsigned myc = (tid < 128) ? c[tid] : 0u;
    if (tid < 128) p[tid] = myc;
    __syncthreads();
    for (int off = 1; off < 128; off <<= 1) {
        unsigned u = 0;
        if (tid < 128 && tid >= off) u = p[tid - off];
        __syncthreads();
        if (tid < 128) p[tid] += u;
        __syncthreads();
    }
    if (tid < 128) {
        unsigned excl = p[tid] - myc;
        run[tid] = excl;
        if (tid < nodes) {
            rp[n0 + tid] = e0 + excl;
            dinv[n0 + tid] = rsqrtf((float)(myc + 1u));
        }
    }
    if (k == 0 && tid == 0) rp[NN] = NE;
    __syncthreads();

    for (unsigned e = e0 + tid; e < e1; e += 256) {
        unsigned v = part[e];
        unsigned dlo = (v >> 20) & 127;
        unsigned pos = e0 + atomicAdd(&run[dlo], 1u);
        col[pos] = v & 0xFFFFFu;
    }
}

// One-shot: Wt[n][k] = (fp16) W[k][n]. 64 KB input; tiny.
__global__ void wt_k(const float* __restrict__ W, _Float16* __restrict__ Wt) {
    int idx = blockIdx.x * 256 + threadIdx.x;   // 0..16383
    int n = idx >> 7, k = idx & 127;
    Wt[idx] = (_Float16)W[k * 128 + n];
}

// h' = dinv ⊙ (x @ W1), fp16 output, MFMA 16x16x32 f16.
// Block: 256 thr = 4 waves; 64 rows/block. B-fragments read DIRECTLY from global
// Wt (32 KB fp16 == L1 size; hits after warm-up) — no LDS staging for W.
// LDS = x tile only (17.4 KB) -> ~6 blocks/CU.
// Verified layouts: A[m=lane&15][k=(lane>>4)*8+j], B[k][n=lane&15],
//                   C/D col=lane&15 row=(lane>>4)*4+reg.
__launch_bounds__(256)
__global__ void gemm1_k(const float* __restrict__ x, const _Float16* __restrict__ Wt,
                        const float* __restrict__ dinv, _Float16* __restrict__ h) {
    __shared__ _Float16 xs[64 * 136];   // xs[row][k]; reused as epilogue buffer
    int tid = threadIdx.x;
    int rb = blockIdx.x * 64;
    int w = tid >> 6, lane = tid & 63;
    int m = lane & 15, q4 = lane >> 4;

    // stage x tile (fp32 -> fp16), 64 rows x 128 cols
#pragma unroll
    for (int q = 0; q < 8; q++) {
        int idx = q * 256 + tid;
        int row = idx >> 5;
        int c4 = (idx & 31) * 4;
        int gr = rb + row;
        float4 v = (gr < NN) ? *(const float4*)(x + (size_t)gr * 128 + c4)
                             : make_float4(0, 0, 0, 0);
        half4v hv = { (_Float16)v.x, (_Float16)v.y, (_Float16)v.z, (_Float16)v.w };
        *(half4v*)(&xs[row * 136 + c4]) = hv;
    }
    __syncthreads();

    f32x4 acc[8];
#pragma unroll
    for (int nt = 0; nt < 8; nt++) acc[nt] = (f32x4){0.f, 0.f, 0.f, 0.f};

    const _Float16* arow = &xs[(w * 16 + m) * 136 + q4 * 8];
    const _Float16* brow = Wt + m * 128 + q4 * 8;
#pragma unroll
    for (int kc = 0; kc < 4; kc++) {
        half8 af = *(const half8*)(arow + kc * 32);
#pragma unroll
        for (int nt = 0; nt < 8; nt++) {
            half8 bf = *(const half8*)(brow + nt * 16 * 128 + kc * 32);
            acc[nt] = __builtin_amdgcn_mfma_f32_16x16x32_f16(af, bf, acc[nt], 0, 0, 0);
        }
    }

    // epilogue: scale by dinv[row], fp16, stage in xs, coalesced store
    float dv[4];
#pragma unroll
    for (int r = 0; r < 4; r++) {
        int ri = rb + w * 16 + q4 * 4 + r;
        dv[r] = (ri < NN) ? dinv[ri] : 0.f;
    }
    __syncthreads();  // xs re-use
#pragma unroll
    for (int nt = 0; nt < 8; nt++) {
#pragma unroll
        for (int r = 0; r < 4; r++) {
            xs[(w * 16 + q4 * 4 + r) * 136 + nt * 16 + m] = (_Float16)(acc[nt][r] * dv[r]);
        }
    }
    __syncthreads();
#pragma unroll
    for (int q = 0; q < 4; q++) {
        int idx = q * 256 + tid;
        int row = idx >> 4;
        int c8 = (idx & 15) * 8;
        int gr = rb + row;
        if (gr < NN)
            *(half8*)(h + (size_t)gr * 128 + c8) = *(const half8*)(&xs[row * 136 + c8]);
    }
}

#define GATHER(sv, vv) \
    { unsigned s_ = __builtin_amdgcn_readfirstlane(col[sv]); \
      vv = __half22float2(hb[(size_t)(s_ * 64u + lane)]); }

// Layer-1 aggregation of prescaled h' + bias/ReLU + 128x2 W2 projection.
// One wave per node; lane holds half2. Edge words scalarized (s_load); x16 unroll
// keeps 16 row-gathers in flight per wave.
__launch_bounds__(256)
__global__ void agg1_k(const _Float16* __restrict__ h, const unsigned* __restrict__ rp,
                       const unsigned* __restrict__ col, const float* __restrict__ dinv,
                       const float* __restrict__ b1, const float* __restrict__ W2,
                       float* __restrict__ z) {
    int i = (blockIdx.x * 256 + threadIdx.x) >> 6;
    int lane = threadIdx.x & 63;
    if (i >= NN) return;

    const __half2* hb = (const __half2*)h;
    float di = dinv[i];
    float2 hv = __half22float2(hb[(size_t)i * 64 + lane]);
    float ax = hv.x, ay = hv.y;  // self term h'[i]

    unsigned p0 = __builtin_amdgcn_readfirstlane(rp[i]);
    unsigned p1 = __builtin_amdgcn_readfirstlane(rp[i + 1]);
    unsigned e = p0;
    for (; e + 16 <= p1; e += 16) {
        float2 v0, v1, v2, v3, v4, v5, v6, v7, v8, v9, va, vb, vc, vd, ve, vf;
        GATHER(e, v0)      GATHER(e + 1, v1)  GATHER(e + 2, v2)  GATHER(e + 3, v3)
        GATHER(e + 4, v4)  GATHER(e + 5, v5)  GATHER(e + 6, v6)  GATHER(e + 7, v7)
        GATHER(e + 8, v8)  GATHER(e + 9, v9)  GATHER(e + 10, va) GATHER(e + 11, vb)
        GATHER(e + 12, vc) GATHER(e + 13, vd) GATHER(e + 14, ve) GATHER(e + 15, vf)
        ax += ((v0.x + v1.x) + (v2.x + v3.x)) + ((v4.x + v5.x) + (v6.x + v7.x))
            + ((v8.x + v9.x) + (va.x + vb.x)) + ((vc.x + vd.x) + (ve.x + vf.x));
        ay += ((v0.y + v1.y) + (v2.y + v3.y)) + ((v4.y + v5.y) + (v6.y + v7.y))
            + ((v8.y + v9.y) + (va.y + vb.y)) + ((vc.y + vd.y) + (ve.y + vf.y));
    }
    for (; e + 4 <= p1; e += 4) {
        float2 v0, v1, v2, v3;
        GATHER(e, v0) GATHER(e + 1, v1) GATHER(e + 2, v2) GATHER(e + 3, v3)
        ax += (v0.x + v1.x) + (v2.x + v3.x);
        ay += (v0.y + v1.y) + (v2.y + v3.y);
    }
    for (; e < p1; ++e) {
        float2 v;
        GATHER(e, v)
        ax += v.x;
        ay += v.y;
    }
    ax *= di;
    ay *= di;

    float2 bv = ((const float2*)b1)[lane];
    float h0 = fmaxf(ax + bv.x, 0.f);
    float h1 = fmaxf(ay + bv.y, 0.f);

    float4 w = ((const float4*)W2)[lane];
    float pz0 = fmaf(h0, w.x, h1 * w.z);
    float pz1 = fmaf(h0, w.y, h1 * w.w);
#pragma unroll
    for (int off = 32; off > 0; off >>= 1) {
        pz0 += __shfl_down(pz0, off);
        pz1 += __shfl_down(pz1, off);
    }
    if (lane == 0) {
        float2* zp = (float2*)(z + (size_t)i * 2);
        *zp = make_float2(pz0 * di, pz1 * di);  // prescale for layer-2 aggregation
    }
}

// Layer-2 aggregation over prescaled z'. out[i] = (Σ z'[s] + z'[i]) * dinv[i] + b2.
__launch_bounds__(256)
__global__ void agg2_k(const float* __restrict__ z, const unsigned* __restrict__ rp,
                       const unsigned* __restrict__ col, const float* __restrict__ dinv,
                       const float* __restrict__ b2, float* __restrict__ out) {
    int i = (blockIdx.x * 256 + threadIdx.x) >> 6;
    int lane = threadIdx.x & 63;
    if (i >= NN) return;

    float di = dinv[i];
    unsigned p0 = __builtin_amdgcn_readfirstlane(rp[i]);
    unsigned p1 = __builtin_amdgcn_readfirstlane(rp[i + 1]);
    float a0 = 0.f, a1 = 0.f;
    for (unsigned e = p0 + lane; e < p1; e += 64) {
        unsigned s = col[e];
        float2 v = ((const float2*)z)[s];
        a0 += v.x;
        a1 += v.y;
    }
#pragma unroll
    for (int off = 32; off > 0; off >>= 1) {
        a0 += __shfl_down(a0, off);
        a1 += __shfl_down(a1, off);
    }
    if (lane == 0) {
        float2 zi = ((const float2*)z)[i];
        out[(size_t)i * 2]     = (a0 + zi.x) * di + b2[0];
        out[(size_t)i * 2 + 1] = (a1 + zi.y) * di + b2[1];
    }
}

extern "C" void kernel_launch(void* const* d_in, const int* in_sizes, int n_in,
                              void* d_out, int out_size, void* d_ws, size_t ws_size,
                              hipStream_t stream) {
    const float* x  = (const float*)d_in[0];
    const int*   ei = (const int*)d_in[1];
    const float* W1 = (const float*)d_in[2];
    const float* b1 = (const float*)d_in[3];
    const float* W2 = (const float*)d_in[4];
    const float* b2 = (const float*)d_in[5];
    float* out = (float*)d_out;

    char* ws = (char*)d_ws;
    unsigned* part = (unsigned*)(ws);               // overlaps h, dead before gemm1
    unsigned* offs = (unsigned*)(ws + 6400000);     // overlaps h
    unsigned* base = (unsigned*)(ws + 8100000);     // overlaps h
    _Float16* h    = (_Float16*)(ws);
    float*    z    = (float*)(ws + 25600000);
    float*    dinv = (float*)(ws + 26400000);
    unsigned* rp   = (unsigned*)(ws + 26800000);
    unsigned* col  = (unsigned*)(ws + 27200016);
    _Float16* Wt   = (_Float16*)(ws + 33600016);

    wt_k<<<64, 256, 0, stream>>>(W1, Wt);
    p1_count_k<<<NBLK_P, 256, 0, stream>>>(ei, offs);
    p2a_k<<<NBK, 512, 0, stream>>>(offs, base);
    p2b_k<<<1, 1024, 0, stream>>>(base);
    p3_scatter_k<<<NBLK_P, 256, 0, stream>>>(ei, offs, base, part);
    p4_csr_k<<<NBK, 256, 0, stream>>>(part, base, rp, dinv, col);

    gemm1_k<<<(NN + 63) / 64, 256, 0, stream>>>(x, Wt, dinv, h);
    agg1_k<<<(NN + 3) / 4, 256, 0, stream>>>(h, rp, col, dinv, b1, W2, z);
    agg2_k<<<(NN + 3) / 4, 256, 0, stream>>>(z, rp, col, dinv, b2, out);
}

// Round 9
// 228.411 us; speedup vs baseline: 1.1502x; 1.1502x over previous
//
#include <hip/hip_runtime.h>
#include <hip/hip_fp16.h>
#include <cstdint>
#include <cstddef>

#define NN 100000
#define NE 1600000
#define D 128
#define NBK 782            // ceil(NN / 128) buckets of 128 nodes
#define NBLK_P 200         // partition blocks
#define EPB 8000           // edges per partition block (200*8000 = 1.6M exact)

typedef _Float16 half8 __attribute__((ext_vector_type(8)));
typedef _Float16 half4v __attribute__((ext_vector_type(4)));
typedef float f32x4 __attribute__((ext_vector_type(4)));

// ---------------- workspace layout (bytes) ----------------
// part  : NE u32      @ 0          (6,400,000)   } dead after p4_csr; overlapped by h
// offs  : 200*782 u32 @ 6,400,000  (  625,600)   }
// base  : 783 u32     @ 7,100,000  (    3,132)   }
// h'    : NN*128 f16  @ 0          (25,600,000)  = dinv[row] * (x@W1), written after CSR
// z'    : NN*2 f32    @ 25,600,000 (   800,000)  = dinv[row] * (relu(agg+b1)@W2)
// dinv  : NN f32      @ 26,400,000 (   400,000)
// rp    : NN+1 u32    @ 26,800,000 (   400,004)
// col   : NE u32      @ 27,200,016 ( 6,400,000)
// Wt    : 128*128 f16 @ 33,600,016 (    32,768)  -> total 33,632,784

// P1: per-block LDS histogram over dst buckets (no global atomics).
__launch_bounds__(256)
__global__ void p1_count_k(const int* __restrict__ ei, unsigned* __restrict__ offs) {
    __shared__ unsigned hist[NBK];
    int tid = threadIdx.x, b = blockIdx.x;
    for (int k = tid; k < NBK; k += 256) hist[k] = 0u;
    __syncthreads();
    int e0 = b * EPB;
    for (int i = tid; i < EPB; i += 256) {
        int d = ei[NE + e0 + i];
        atomicAdd(&hist[d >> 7], 1u);
    }
    __syncthreads();
    for (int k = tid; k < NBK; k += 256) offs[(size_t)b * NBK + k] = hist[k];
}

// P2a: block per bucket; parallel loads of the 200 per-block counts + LDS scan.
__launch_bounds__(256)
__global__ void p2a_k(unsigned* __restrict__ offs, unsigned* __restrict__ base) {
    __shared__ unsigned sh[256];
    int t = threadIdx.x, k = blockIdx.x;
    unsigned v = (t < NBLK_P) ? offs[(size_t)t * NBK + k] : 0u;
    sh[t] = v;
    __syncthreads();
    for (int off = 1; off < 256; off <<= 1) {
        unsigned u = (t >= off) ? sh[t - off] : 0u;
        __syncthreads();
        sh[t] += u;
        __syncthreads();
    }
    if (t < NBLK_P) offs[(size_t)t * NBK + k] = sh[t] - v;  // exclusive
    if (t == 255) base[k] = sh[255];                         // bucket total
}

// P2b: exclusive scan of bucket totals; base[NBK] = NE.
__global__ void p2b_k(unsigned* __restrict__ base) {
    __shared__ unsigned sh[1024];
    int t = threadIdx.x;
    unsigned v = (t < NBK) ? base[t] : 0u;
    sh[t] = v;
    __syncthreads();
    for (int off = 1; off < 1024; off <<= 1) {
        unsigned u = (t >= off) ? sh[t - off] : 0u;
        __syncthreads();
        sh[t] += u;
        __syncthreads();
    }
    if (t < NBK) base[t] = sh[t] - v;
    if (t == NBK) base[NBK] = sh[NBK - 1];
}

// P3: scatter packed edges into bucket-partitioned order via LDS running counters.
__launch_bounds__(256)
__global__ void p3_scatter_k(const int* __restrict__ ei, const unsigned* __restrict__ offs,
                             const unsigned* __restrict__ base, unsigned* __restrict__ part) {
    __shared__ unsigned lcnt[NBK];
    int tid = threadIdx.x, b = blockIdx.x;
    for (int k = tid; k < NBK; k += 256) lcnt[k] = base[k] + offs[(size_t)b * NBK + k];
    __syncthreads();
    int e0 = b * EPB;
    for (int i = tid; i < EPB; i += 256) {
        int s = ei[e0 + i];
        int d = ei[NE + e0 + i];
        unsigned pos = atomicAdd(&lcnt[d >> 7], 1u);
        part[pos] = (unsigned)s | ((unsigned)(d & 127) << 20);
    }
}

// P4: one block per bucket. Count per node in LDS, scan, emit rp/dinv, regroup col.
__launch_bounds__(256)
__global__ void p4_csr_k(const unsigned* __restrict__ part, const unsigned* __restrict__ base,
                         unsigned* __restrict__ rp, float* __restrict__ dinv,
                         unsigned* __restrict__ col) {
    __shared__ unsigned c[128], p[128], run[128];
    int tid = threadIdx.x, k = blockIdx.x;
    int n0 = k << 7;
    int nodes = (NN - n0 < 128) ? (NN - n0) : 128;
    unsigned e0 = base[k], e1 = base[k + 1];

    if (tid < 128) c[tid] = 0u;
    __syncthreads();
    for (unsigned e = e0 + tid; e < e1; e += 256)
        atomicAdd(&c[(part[e] >> 20) & 127], 1u);
    __syncthreads();

    unsigned myc = (tid < 128) ? c[tid] : 0u;
    if (tid < 128) p[tid] = myc;
    __syncthreads();
    for (int off = 1; off < 128; off <<= 1) {
        unsigned u = 0;
        if (tid < 128 && tid >= off) u = p[tid - off];
        __syncthreads();
        if (tid < 128) p[tid] += u;
        __syncthreads();
    }
    if (tid < 128) {
        unsigned excl = p[tid] - myc;
        run[tid] = excl;
        if (tid < nodes) {
            rp[n0 + tid] = e0 + excl;
            dinv[n0 + tid] = rsqrtf((float)(myc + 1u));
        }
    }
    if (k == 0 && tid == 0) rp[NN] = NE;
    __syncthreads();

    for (unsigned e = e0 + tid; e < e1; e += 256) {
        unsigned v = part[e];
        unsigned dlo = (v >> 20) & 127;
        unsigned pos = e0 + atomicAdd(&run[dlo], 1u);
        col[pos] = v & 0xFFFFFu;
    }
}

// One-shot: Wt[n][k] = (fp16) W[k][n]. 64 KB input; tiny.
__global__ void wt_k(const float* __restrict__ W, _Float16* __restrict__ Wt) {
    int idx = blockIdx.x * 256 + threadIdx.x;   // 0..16383
    int n = idx >> 7, k = idx & 127;
    Wt[idx] = (_Float16)W[k * 128 + n];
}

// h' = dinv ⊙ (x @ W1), fp16 output, MFMA 16x16x32 f16.
// Block: 256 thr = 4 waves; 64 rows/block. Wt preloaded (fp16, transposed),
// staged to LDS with coalesced half8 copies — LDS pins the reuse (L1 cannot:
// the streaming x-tile evicts it; measured +20us when read from global).
__launch_bounds__(256)
__global__ void gemm1_k(const float* __restrict__ x, const _Float16* __restrict__ Wt,
                        const float* __restrict__ dinv, _Float16* __restrict__ h) {
    __shared__ _Float16 wt[128 * 136];  // wt[n][k]
    __shared__ _Float16 xs[64 * 136];   // xs[row][k]; reused as epilogue buffer
    int tid = threadIdx.x;
    int rb = blockIdx.x * 64;
    int w = tid >> 6, lane = tid & 63;
    int m = lane & 15, q4 = lane >> 4;

    // stage Wt: 2048 half8 chunks, coalesced global, conflict-free LDS
#pragma unroll
    for (int q = 0; q < 8; q++) {
        int idx = q * 256 + tid;          // 0..2047
        int n  = idx >> 4;
        int k8 = (idx & 15) * 8;
        *(half8*)(&wt[n * 136 + k8]) = *(const half8*)(Wt + n * 128 + k8);
    }
    // stage x tile (fp32 -> fp16), 64 rows x 128 cols
#pragma unroll
    for (int q = 0; q < 8; q++) {
        int idx = q * 256 + tid;
        int row = idx >> 5;
        int c4 = (idx & 31) * 4;
        int gr = rb + row;
        float4 v = (gr < NN) ? *(const float4*)(x + (size_t)gr * 128 + c4)
                             : make_float4(0, 0, 0, 0);
        half4v hv = { (_Float16)v.x, (_Float16)v.y, (_Float16)v.z, (_Float16)v.w };
        *(half4v*)(&xs[row * 136 + c4]) = hv;
    }
    __syncthreads();

    f32x4 acc[8];
#pragma unroll
    for (int nt = 0; nt < 8; nt++) acc[nt] = (f32x4){0.f, 0.f, 0.f, 0.f};

    const _Float16* arow = &xs[(w * 16 + m) * 136 + q4 * 8];
#pragma unroll
    for (int kc = 0; kc < 4; kc++) {
        half8 af = *(const half8*)(arow + kc * 32);
#pragma unroll
        for (int nt = 0; nt < 8; nt++) {
            half8 bf = *(const half8*)(&wt[(nt * 16 + m) * 136 + q4 * 8 + kc * 32]);
            acc[nt] = __builtin_amdgcn_mfma_f32_16x16x32_f16(af, bf, acc[nt], 0, 0, 0);
        }
    }

    // epilogue: scale by dinv[row], fp16, stage in xs, coalesced store
    float dv[4];
#pragma unroll
    for (int r = 0; r < 4; r++) {
        int ri = rb + w * 16 + q4 * 4 + r;
        dv[r] = (ri < NN) ? dinv[ri] : 0.f;
    }
    __syncthreads();  // xs re-use
#pragma unroll
    for (int nt = 0; nt < 8; nt++) {
#pragma unroll
        for (int r = 0; r < 4; r++) {
            xs[(w * 16 + q4 * 4 + r) * 136 + nt * 16 + m] = (_Float16)(acc[nt][r] * dv[r]);
        }
    }
    __syncthreads();
#pragma unroll
    for (int q = 0; q < 4; q++) {
        int idx = q * 256 + tid;
        int row = idx >> 4;
        int c8 = (idx & 15) * 8;
        int gr = rb + row;
        if (gr < NN)
            *(half8*)(h + (size_t)gr * 128 + c8) = *(const half8*)(&xs[row * 136 + c8]);
    }
}

#define GATHER(sv, vv) \
    { unsigned s_ = __builtin_amdgcn_readfirstlane(col[sv]); \
      vv = __half22float2(hb[(size_t)(s_ * 64u + lane)]); }

// Layer-1 aggregation of prescaled h' + bias/ReLU + 128x2 W2 projection.
// One wave per node; lane holds half2. Edge words scalarized (s_load); x16 unroll
// keeps 16 row-gathers in flight per wave.
__launch_bounds__(256)
__global__ void agg1_k(const _Float16* __restrict__ h, const unsigned* __restrict__ rp,
                       const unsigned* __restrict__ col, const float* __restrict__ dinv,
                       const float* __restrict__ b1, const float* __restrict__ W2,
                       float* __restrict__ z) {
    int i = (blockIdx.x * 256 + threadIdx.x) >> 6;
    int lane = threadIdx.x & 63;
    if (i >= NN) return;

    const __half2* hb = (const __half2*)h;
    float di = dinv[i];
    float2 hv = __half22float2(hb[(size_t)i * 64 + lane]);
    float ax = hv.x, ay = hv.y;  // self term h'[i]

    unsigned p0 = __builtin_amdgcn_readfirstlane(rp[i]);
    unsigned p1 = __builtin_amdgcn_readfirstlane(rp[i + 1]);
    unsigned e = p0;
    for (; e + 16 <= p1; e += 16) {
        float2 v0, v1, v2, v3, v4, v5, v6, v7, v8, v9, va, vb, vc, vd, ve, vf;
        GATHER(e, v0)      GATHER(e + 1, v1)  GATHER(e + 2, v2)  GATHER(e + 3, v3)
        GATHER(e + 4, v4)  GATHER(e + 5, v5)  GATHER(e + 6, v6)  GATHER(e + 7, v7)
        GATHER(e + 8, v8)  GATHER(e + 9, v9)  GATHER(e + 10, va) GATHER(e + 11, vb)
        GATHER(e + 12, vc) GATHER(e + 13, vd) GATHER(e + 14, ve) GATHER(e + 15, vf)
        ax += ((v0.x + v1.x) + (v2.x + v3.x)) + ((v4.x + v5.x) + (v6.x + v7.x))
            + ((v8.x + v9.x) + (va.x + vb.x)) + ((vc.x + vd.x) + (ve.x + vf.x));
        ay += ((v0.y + v1.y) + (v2.y + v3.y)) + ((v4.y + v5.y) + (v6.y + v7.y))
            + ((v8.y + v9.y) + (va.y + vb.y)) + ((vc.y + vd.y) + (ve.y + vf.y));
    }
    for (; e + 4 <= p1; e += 4) {
        float2 v0, v1, v2, v3;
        GATHER(e, v0) GATHER(e + 1, v1) GATHER(e + 2, v2) GATHER(e + 3, v3)
        ax += (v0.x + v1.x) + (v2.x + v3.x);
        ay += (v0.y + v1.y) + (v2.y + v3.y);
    }
    for (; e < p1; ++e) {
        float2 v;
        GATHER(e, v)
        ax += v.x;
        ay += v.y;
    }
    ax *= di;
    ay *= di;

    float2 bv = ((const float2*)b1)[lane];
    float h0 = fmaxf(ax + bv.x, 0.f);
    float h1 = fmaxf(ay + bv.y, 0.f);

    float4 w = ((const float4*)W2)[lane];
    float pz0 = fmaf(h0, w.x, h1 * w.z);
    float pz1 = fmaf(h0, w.y, h1 * w.w);
#pragma unroll
    for (int off = 32; off > 0; off >>= 1) {
        pz0 += __shfl_down(pz0, off);
        pz1 += __shfl_down(pz1, off);
    }
    if (lane == 0) {
        float2* zp = (float2*)(z + (size_t)i * 2);
        *zp = make_float2(pz0 * di, pz1 * di);  // prescale for layer-2 aggregation
    }
}

// Layer-2 aggregation over prescaled z'. 16 lanes per node (avg degree 16):
// 4 nodes/wave, width-16 shuffle reduce. out[i] = (Σ z'[s] + z'[i])*dinv[i] + b2.
__launch_bounds__(256)
__global__ void agg2_k(const float* __restrict__ z, const unsigned* __restrict__ rp,
                       const unsigned* __restrict__ col, const float* __restrict__ dinv,
                       const float* __restrict__ b2, float* __restrict__ out) {
    int i = (blockIdx.x * 256 + threadIdx.x) >> 4;
    int sl = threadIdx.x & 15;
    if (i >= NN) return;

    unsigned p0 = rp[i], p1 = rp[i + 1];
    float a0 = 0.f, a1 = 0.f;
    for (unsigned e = p0 + sl; e < p1; e += 16) {
        unsigned s = col[e];
        float2 v = ((const float2*)z)[s];
        a0 += v.x;
        a1 += v.y;
    }
#pragma unroll
    for (int off = 8; off > 0; off >>= 1) {
        a0 += __shfl_down(a0, off, 16);
        a1 += __shfl_down(a1, off, 16);
    }
    if (sl == 0) {
        float di = dinv[i];
        float2 zi = ((const float2*)z)[i];
        out[(size_t)i * 2]     = (a0 + zi.x) * di + b2[0];
        out[(size_t)i * 2 + 1] = (a1 + zi.y) * di + b2[1];
    }
}

extern "C" void kernel_launch(void* const* d_in, const int* in_sizes, int n_in,
                              void* d_out, int out_size, void* d_ws, size_t ws_size,
                              hipStream_t stream) {
    const float* x  = (const float*)d_in[0];
    const int*   ei = (const int*)d_in[1];
    const float* W1 = (const float*)d_in[2];
    const float* b1 = (const float*)d_in[3];
    const float* W2 = (const float*)d_in[4];
    const float* b2 = (const float*)d_in[5];
    float* out = (float*)d_out;

    char* ws = (char*)d_ws;
    unsigned* part = (unsigned*)(ws);               // overlaps h, dead before gemm1
    unsigned* offs = (unsigned*)(ws + 6400000);     // overlaps h
    unsigned* base = (unsigned*)(ws + 7100000);     // overlaps h
    _Float16* h    = (_Float16*)(ws);
    float*    z    = (float*)(ws + 25600000);
    float*    dinv = (float*)(ws + 26400000);
    unsigned* rp   = (unsigned*)(ws + 26800000);
    unsigned* col  = (unsigned*)(ws + 27200016);
    _Float16* Wt   = (_Float16*)(ws + 33600016);

    wt_k<<<64, 256, 0, stream>>>(W1, Wt);
    p1_count_k<<<NBLK_P, 256, 0, stream>>>(ei, offs);
    p2a_k<<<NBK, 256, 0, stream>>>(offs, base);
    p2b_k<<<1, 1024, 0, stream>>>(base);
    p3_scatter_k<<<NBLK_P, 256, 0, stream>>>(ei, offs, base, part);
    p4_csr_k<<<NBK, 256, 0, stream>>>(part, base, rp, dinv, col);

    gemm1_k<<<(NN + 63) / 64, 256, 0, stream>>>(x, Wt, dinv, h);
    agg1_k<<<(NN + 3) / 4, 256, 0, stream>>>(h, rp, col, dinv, b1, W2, z);
    agg2_k<<<(NN * 16 + 255) / 256, 256, 0, stream>>>(z, rp, col, dinv, b2, out);
}

// Round 10
// 223.929 us; speedup vs baseline: 1.1732x; 1.0200x over previous
//
#include <hip/hip_runtime.h>
#include <hip/hip_fp16.h>
#include <cstdint>
#include <cstddef>

#define NN 100000
#define NE 1600000
#define D 128
#define NBK 782            // ceil(NN / 128) buckets of 128 nodes
#define NBLK_P 200         // partition blocks
#define EPB 8000           // edges per partition block (200*8000 = 1.6M exact)

typedef _Float16 half8 __attribute__((ext_vector_type(8)));
typedef _Float16 half4v __attribute__((ext_vector_type(4)));
typedef float f32x4 __attribute__((ext_vector_type(4)));

// ---------------- workspace layout (bytes) ----------------
// part  : NE u32      @ 0          (6,400,000)   } dead after p4_csr; overlapped by h
// offs  : 200*782 u32 @ 6,400,000  (  625,600)   }
// base  : 783 u32     @ 7,100,000  (    3,132)   }
// h'    : NN*128 f16  @ 0          (25,600,000)  = dinv[row] * (x@W1), written after CSR
// z'    : NN*2 f32    @ 25,600,000 (   800,000)  = dinv[row] * (relu(agg+b1)@W2)
// dinv  : NN f32      @ 26,400,000 (   400,000)
// rp    : NN+1 u32    @ 26,800,000 (   400,004)
// col   : NE u32      @ 27,200,016 ( 6,400,000)
// Wt    : 128*128 f16 @ 33,600,016 (    32,768)  -> total 33,632,784

// P1: per-block LDS histogram over dst buckets (int4 edge loads, no global atomics).
// Blocks 0..63 additionally emit Wt[n][k] = fp16 W1[k][n] (fused wt_k).
__launch_bounds__(256)
__global__ void p1_count_k(const int* __restrict__ ei, unsigned* __restrict__ offs,
                           const float* __restrict__ W, _Float16* __restrict__ Wt) {
    __shared__ unsigned hist[NBK];
    int tid = threadIdx.x, b = blockIdx.x;
    for (int k = tid; k < NBK; k += 256) hist[k] = 0u;
    __syncthreads();
    int e0 = b * EPB;
    for (int i = tid * 4; i < EPB; i += 1024) {
        int4 d4 = *(const int4*)(ei + NE + e0 + i);
        atomicAdd(&hist[d4.x >> 7], 1u);
        atomicAdd(&hist[d4.y >> 7], 1u);
        atomicAdd(&hist[d4.z >> 7], 1u);
        atomicAdd(&hist[d4.w >> 7], 1u);
    }
    __syncthreads();
    for (int k = tid; k < NBK; k += 256) offs[(size_t)b * NBK + k] = hist[k];

    if (b < 64) {  // fused Wt transpose+cast (16384 elems over 64 blocks)
        int idx = b * 256 + tid;
        int n = idx >> 7, k = idx & 127;
        Wt[idx] = (_Float16)W[k * 128 + n];
    }
}

// P2a: block per bucket; parallel loads of the 200 per-block counts + LDS scan.
__launch_bounds__(256)
__global__ void p2a_k(unsigned* __restrict__ offs, unsigned* __restrict__ base) {
    __shared__ unsigned sh[256];
    int t = threadIdx.x, k = blockIdx.x;
    unsigned v = (t < NBLK_P) ? offs[(size_t)t * NBK + k] : 0u;
    sh[t] = v;
    __syncthreads();
    for (int off = 1; off < 256; off <<= 1) {
        unsigned u = (t >= off) ? sh[t - off] : 0u;
        __syncthreads();
        sh[t] += u;
        __syncthreads();
    }
    if (t < NBLK_P) offs[(size_t)t * NBK + k] = sh[t] - v;  // exclusive
    if (t == 255) base[k] = sh[255];                         // bucket total
}

// P2b: exclusive scan of bucket totals; base[NBK] = NE.
__global__ void p2b_k(unsigned* __restrict__ base) {
    __shared__ unsigned sh[1024];
    int t = threadIdx.x;
    unsigned v = (t < NBK) ? base[t] : 0u;
    sh[t] = v;
    __syncthreads();
    for (int off = 1; off < 1024; off <<= 1) {
        unsigned u = (t >= off) ? sh[t - off] : 0u;
        __syncthreads();
        sh[t] += u;
        __syncthreads();
    }
    if (t < NBK) base[t] = sh[t] - v;
    if (t == NBK) base[NBK] = sh[NBK - 1];
}

// P3: scatter packed edges into bucket-partitioned order via LDS running counters.
__launch_bounds__(256)
__global__ void p3_scatter_k(const int* __restrict__ ei, const unsigned* __restrict__ offs,
                             const unsigned* __restrict__ base, unsigned* __restrict__ part) {
    __shared__ unsigned lcnt[NBK];
    int tid = threadIdx.x, b = blockIdx.x;
    for (int k = tid; k < NBK; k += 256) lcnt[k] = base[k] + offs[(size_t)b * NBK + k];
    __syncthreads();
    int e0 = b * EPB;
    for (int i = tid * 4; i < EPB; i += 1024) {
        int4 s4 = *(const int4*)(ei + e0 + i);
        int4 d4 = *(const int4*)(ei + NE + e0 + i);
        unsigned p;
        p = atomicAdd(&lcnt[d4.x >> 7], 1u); part[p] = (unsigned)s4.x | ((unsigned)(d4.x & 127) << 20);
        p = atomicAdd(&lcnt[d4.y >> 7], 1u); part[p] = (unsigned)s4.y | ((unsigned)(d4.y & 127) << 20);
        p = atomicAdd(&lcnt[d4.z >> 7], 1u); part[p] = (unsigned)s4.z | ((unsigned)(d4.z & 127) << 20);
        p = atomicAdd(&lcnt[d4.w >> 7], 1u); part[p] = (unsigned)s4.w | ((unsigned)(d4.w & 127) << 20);
    }
}

// P4: one block per bucket. Count per node in LDS, scan, emit rp/dinv, regroup col.
__launch_bounds__(256)
__global__ void p4_csr_k(const unsigned* __restrict__ part, const unsigned* __restrict__ base,
                         unsigned* __restrict__ rp, float* __restrict__ dinv,
                         unsigned* __restrict__ col) {
    __shared__ unsigned c[128], p[128], run[128];
    int tid = threadIdx.x, k = blockIdx.x;
    int n0 = k << 7;
    int nodes = (NN - n0 < 128) ? (NN - n0) : 128;
    unsigned e0 = base[k], e1 = base[k + 1];

    if (tid < 128) c[tid] = 0u;
    __syncthreads();
    for (unsigned e = e0 + tid; e < e1; e += 256)
        atomicAdd(&c[(part[e] >> 20) & 127], 1u);
    __syncthreads();

    unsigned myc = (tid < 128) ? c[tid] : 0u;
    if (tid < 128) p[tid] = myc;
    __syncthreads();
    for (int off = 1; off < 128; off <<= 1) {
        unsigned u = 0;
        if (tid < 128 && tid >= off) u = p[tid - off];
        __syncthreads();
        if (tid < 128) p[tid] += u;
        __syncthreads();
    }
    if (tid < 128) {
        unsigned excl = p[tid] - myc;
        run[tid] = excl;
        if (tid < nodes) {
            rp[n0 + tid] = e0 + excl;
            dinv[n0 + tid] = rsqrtf((float)(myc + 1u));
        }
    }
    if (k == 0 && tid == 0) rp[NN] = NE;
    __syncthreads();

    for (unsigned e = e0 + tid; e < e1; e += 256) {
        unsigned v = part[e];
        unsigned dlo = (v >> 20) & 127;
        unsigned pos = e0 + atomicAdd(&run[dlo], 1u);
        col[pos] = v & 0xFFFFFu;
    }
}

// h' = dinv ⊙ (x @ W1), fp16 out, MFMA 16x16x32 f16. 128 rows/block, 4 waves;
// wave w covers rows w*32..w*32+31 (2 row-tiles) × all 8 col-tiles -> B-frag
// reused across 2 MFMAs. x staged in K-halves of 64 so LDS = 34.8K (wt) +
// 18.4K (xs) = 52K -> 3 blocks/CU; 782 blocks ≈ one co-resident round.
// Verified layouts: A[m=lane&15][k=(lane>>4)*8+j], B[k][n=lane&15],
//                   C/D col=lane&15 row=(lane>>4)*4+reg.
__launch_bounds__(256)
__global__ void gemm1_k(const float* __restrict__ x, const _Float16* __restrict__ Wt,
                        const float* __restrict__ dinv, _Float16* __restrict__ h) {
    __shared__ _Float16 wt[128 * 136];  // B: wt[n][k]; reused as epilogue buffer
    __shared__ _Float16 xs[128 * 72];   // A: xs[row][k within 64-half]
    int tid = threadIdx.x;
    int rb = blockIdx.x * 128;
    int w = tid >> 6, lane = tid & 63;
    int m = lane & 15, q4 = lane >> 4;

    // stage Wt: 2048 half8 chunks, coalesced global, conflict-free LDS
#pragma unroll
    for (int q = 0; q < 8; q++) {
        int idx = q * 256 + tid;
        int n = idx >> 4, k8 = (idx & 15) * 8;
        *(half8*)(&wt[n * 136 + k8]) = *(const half8*)(Wt + n * 128 + k8);
    }

    f32x4 acc[2][8];
#pragma unroll
    for (int rt = 0; rt < 2; rt++)
#pragma unroll
        for (int nt = 0; nt < 8; nt++) acc[rt][nt] = (f32x4){0.f, 0.f, 0.f, 0.f};

    for (int ks = 0; ks <= 64; ks += 64) {
        if (ks) __syncthreads();  // previous xs fully consumed
        // stage x rows [rb, rb+128) cols [ks, ks+64), fp32 -> fp16
#pragma unroll
        for (int q = 0; q < 8; q++) {
            int idx = q * 256 + tid;        // 0..2047
            int row = idx >> 4;
            int c4 = (idx & 15) * 4;
            int gr = rb + row;
            float4 v = (gr < NN) ? *(const float4*)(x + (size_t)gr * 128 + ks + c4)
                                 : make_float4(0, 0, 0, 0);
            half4v hv = { (_Float16)v.x, (_Float16)v.y, (_Float16)v.z, (_Float16)v.w };
            *(half4v*)(&xs[row * 72 + c4]) = hv;
        }
        __syncthreads();

#pragma unroll
        for (int kc = 0; kc < 2; kc++) {
            half8 a0 = *(const half8*)(&xs[(w * 32 + m) * 72 + kc * 32 + q4 * 8]);
            half8 a1 = *(const half8*)(&xs[(w * 32 + 16 + m) * 72 + kc * 32 + q4 * 8]);
#pragma unroll
            for (int nt = 0; nt < 8; nt++) {
                half8 bf = *(const half8*)(&wt[(nt * 16 + m) * 136 + ks + kc * 32 + q4 * 8]);
                acc[0][nt] = __builtin_amdgcn_mfma_f32_16x16x32_f16(a0, bf, acc[0][nt], 0, 0, 0);
                acc[1][nt] = __builtin_amdgcn_mfma_f32_16x16x32_f16(a1, bf, acc[1][nt], 0, 0, 0);
            }
        }
    }

    // epilogue: scale by dinv[row], fp16, stage in wt (dead), coalesced store
    float dv[2][4];
#pragma unroll
    for (int rt = 0; rt < 2; rt++)
#pragma unroll
        for (int r = 0; r < 4; r++) {
            int ri = rb + w * 32 + rt * 16 + q4 * 4 + r;
            dv[rt][r] = (ri < NN) ? dinv[ri] : 0.f;
        }
    __syncthreads();  // all wt reads done
#pragma unroll
    for (int rt = 0; rt < 2; rt++)
#pragma unroll
        for (int nt = 0; nt < 8; nt++)
#pragma unroll
            for (int r = 0; r < 4; r++)
                wt[(w * 32 + rt * 16 + q4 * 4 + r) * 136 + nt * 16 + m] =
                    (_Float16)(acc[rt][nt][r] * dv[rt][r]);
    __syncthreads();
#pragma unroll
    for (int q = 0; q < 8; q++) {
        int idx = q * 256 + tid;
        int row = idx >> 4;
        int c8 = (idx & 15) * 8;
        int gr = rb + row;
        if (gr < NN)
            *(half8*)(h + (size_t)gr * 128 + c8) = *(const half8*)(&wt[row * 136 + c8]);
    }
}

#define GATHER(sv, vv) \
    { unsigned s_ = __builtin_amdgcn_readfirstlane(col[sv]); \
      vv = __half22float2(hb[(size_t)(s_ * 64u + lane)]); }

// Layer-1 aggregation of prescaled h' + bias/ReLU + 128x2 W2 projection.
// One wave per node; lane holds half2. Edge words scalarized (s_load); x16 unroll
// keeps 16 row-gathers in flight per wave.
__launch_bounds__(256)
__global__ void agg1_k(const _Float16* __restrict__ h, const unsigned* __restrict__ rp,
                       const unsigned* __restrict__ col, const float* __restrict__ dinv,
                       const float* __restrict__ b1, const float* __restrict__ W2,
                       float* __restrict__ z) {
    int i = (blockIdx.x * 256 + threadIdx.x) >> 6;
    int lane = threadIdx.x & 63;
    if (i >= NN) return;

    const __half2* hb = (const __half2*)h;
    float di = dinv[i];
    float2 hv = __half22float2(hb[(size_t)i * 64 + lane]);
    float ax = hv.x, ay = hv.y;  // self term h'[i]

    unsigned p0 = __builtin_amdgcn_readfirstlane(rp[i]);
    unsigned p1 = __builtin_amdgcn_readfirstlane(rp[i + 1]);
    unsigned e = p0;
    for (; e + 16 <= p1; e += 16) {
        float2 v0, v1, v2, v3, v4, v5, v6, v7, v8, v9, va, vb, vc, vd, ve, vf;
        GATHER(e, v0)      GATHER(e + 1, v1)  GATHER(e + 2, v2)  GATHER(e + 3, v3)
        GATHER(e + 4, v4)  GATHER(e + 5, v5)  GATHER(e + 6, v6)  GATHER(e + 7, v7)
        GATHER(e + 8, v8)  GATHER(e + 9, v9)  GATHER(e + 10, va) GATHER(e + 11, vb)
        GATHER(e + 12, vc) GATHER(e + 13, vd) GATHER(e + 14, ve) GATHER(e + 15, vf)
        ax += ((v0.x + v1.x) + (v2.x + v3.x)) + ((v4.x + v5.x) + (v6.x + v7.x))
            + ((v8.x + v9.x) + (va.x + vb.x)) + ((vc.x + vd.x) + (ve.x + vf.x));
        ay += ((v0.y + v1.y) + (v2.y + v3.y)) + ((v4.y + v5.y) + (v6.y + v7.y))
            + ((v8.y + v9.y) + (va.y + vb.y)) + ((vc.y + vd.y) + (ve.y + vf.y));
    }
    for (; e + 4 <= p1; e += 4) {
        float2 v0, v1, v2, v3;
        GATHER(e, v0) GATHER(e + 1, v1) GATHER(e + 2, v2) GATHER(e + 3, v3)
        ax += (v0.x + v1.x) + (v2.x + v3.x);
        ay += (v0.y + v1.y) + (v2.y + v3.y);
    }
    for (; e < p1; ++e) {
        float2 v;
        GATHER(e, v)
        ax += v.x;
        ay += v.y;
    }
    ax *= di;
    ay *= di;

    float2 bv = ((const float2*)b1)[lane];
    float h0 = fmaxf(ax + bv.x, 0.f);
    float h1 = fmaxf(ay + bv.y, 0.f);

    float4 w = ((const float4*)W2)[lane];
    float pz0 = fmaf(h0, w.x, h1 * w.z);
    float pz1 = fmaf(h0, w.y, h1 * w.w);
#pragma unroll
    for (int off = 32; off > 0; off >>= 1) {
        pz0 += __shfl_down(pz0, off);
        pz1 += __shfl_down(pz1, off);
    }
    if (lane == 0) {
        float2* zp = (float2*)(z + (size_t)i * 2);
        *zp = make_float2(pz0 * di, pz1 * di);  // prescale for layer-2 aggregation
    }
}

// Layer-2 aggregation over prescaled z'. 16 lanes per node (avg degree 16):
// 4 nodes/wave, width-16 shuffle reduce. out[i] = (Σ z'[s] + z'[i])*dinv[i] + b2.
__launch_bounds__(256)
__global__ void agg2_k(const float* __restrict__ z, const unsigned* __restrict__ rp,
                       const unsigned* __restrict__ col, const float* __restrict__ dinv,
                       const float* __restrict__ b2, float* __restrict__ out) {
    int i = (blockIdx.x * 256 + threadIdx.x) >> 4;
    int sl = threadIdx.x & 15;
    if (i >= NN) return;

    unsigned p0 = rp[i], p1 = rp[i + 1];
    float a0 = 0.f, a1 = 0.f;
    for (unsigned e = p0 + sl; e < p1; e += 16) {
        unsigned s = col[e];
        float2 v = ((const float2*)z)[s];
        a0 += v.x;
        a1 += v.y;
    }
#pragma unroll
    for (int off = 8; off > 0; off >>= 1) {
        a0 += __shfl_down(a0, off, 16);
        a1 += __shfl_down(a1, off, 16);
    }
    if (sl == 0) {
        float di = dinv[i];
        float2 zi = ((const float2*)z)[i];
        out[(size_t)i * 2]     = (a0 + zi.x) * di + b2[0];
        out[(size_t)i * 2 + 1] = (a1 + zi.y) * di + b2[1];
    }
}

extern "C" void kernel_launch(void* const* d_in, const int* in_sizes, int n_in,
                              void* d_out, int out_size, void* d_ws, size_t ws_size,
                              hipStream_t stream) {
    const float* x  = (const float*)d_in[0];
    const int*   ei = (const int*)d_in[1];
    const float* W1 = (const float*)d_in[2];
    const float* b1 = (const float*)d_in[3];
    const float* W2 = (const float*)d_in[4];
    const float* b2 = (const float*)d_in[5];
    float* out = (float*)d_out;

    char* ws = (char*)d_ws;
    unsigned* part = (unsigned*)(ws);               // overlaps h, dead before gemm1
    unsigned* offs = (unsigned*)(ws + 6400000);     // overlaps h
    unsigned* base = (unsigned*)(ws + 7100000);     // overlaps h
    _Float16* h    = (_Float16*)(ws);
    float*    z    = (float*)(ws + 25600000);
    float*    dinv = (float*)(ws + 26400000);
    unsigned* rp   = (unsigned*)(ws + 26800000);
    unsigned* col  = (unsigned*)(ws + 27200016);
    _Float16* Wt   = (_Float16*)(ws + 33600016);

    p1_count_k<<<NBLK_P, 256, 0, stream>>>(ei, offs, W1, Wt);
    p2a_k<<<NBK, 256, 0, stream>>>(offs, base);
    p2b_k<<<1, 1024, 0, stream>>>(base);
    p3_scatter_k<<<NBLK_P, 256, 0, stream>>>(ei, offs, base, part);
    p4_csr_k<<<NBK, 256, 0, stream>>>(part, base, rp, dinv, col);

    gemm1_k<<<(NN + 127) / 128, 256, 0, stream>>>(x, Wt, dinv, h);
    agg1_k<<<(NN + 3) / 4, 256, 0, stream>>>(h, rp, col, dinv, b1, W2, z);
    agg2_k<<<(NN * 16 + 255) / 256, 256, 0, stream>>>(z, rp, col, dinv, b2, out);
}